// Round 12
// baseline (220.867 us; speedup 1.0000x reference)
//
#include <hip/hip_runtime.h>

// Legendre projection: out[n, dim*128 + deg] = P_deg(2*x[n,dim] - 1)
// 1,048,576 (n,dim) segments x 128 fp32 = 512 MiB output. Write-bound.
// Plateau 101-105 us (~5.35 TB/s) across SEVEN structural levers:
// scatter/contig drain, 128B/256B runs, 4-32 waves/CU, nt/plain,
// persistent grid. Memset reference (fillBufferAligned, constant data):
// 6.7 TB/s. R12 = R11 (101.4 us, unchanged) + a DIAGNOSTIC probe:
// memset-identical plain-HIP grid-stride constant stores, 512 MB into
// d_ws. Total dur_us ~177 => HIP constant stores hit 6.7 (keep hunting);
// total ~196 => 6.7 unreachable from HIP => R11 is the ceiling.

#define DEG1 128

typedef float f32x4 __attribute__((ext_vector_type(4)));
typedef unsigned int u32x4 __attribute__((ext_vector_type(4)));

__global__ __launch_bounds__(256) void LegendreProjection_48644799594943_kernel(
    const float* __restrict__ x, float* __restrict__ out) {
    // Per wave: 64 segs x 16 f32x4 (one 64-degree chunk) = 16 KB.
    // Flat idx = seg*16 + (w ^ (seg&15)); conflict-free b128 both sides.
    __shared__ f32x4 lds[4][1024];

    const int tid  = threadIdx.x;
    const int wave = tid >> 6;
    const int lane = tid & 63;
    const int seg0 = (blockIdx.x * 4 + wave) * 64;  // this wave's 64 segments

    const float xs = 2.0f * x[seg0 + lane] - 1.0f;

    f32x4* my = lds[wave];
    f32x4* outv = reinterpret_cast<f32x4*>(out);

    float pm = 1.0f;  // P_{deg-1}
    float pc = xs;    // P_deg

#pragma unroll
    for (int c = 0; c < 2; ++c) {
        // --- compute 64 degrees for my segment, write swizzled to LDS ---
#pragma unroll
        for (int w = 0; w < 16; ++w) {
            f32x4 q;
#pragma unroll
            for (int j = 0; j < 4; ++j) {
                const int deg = c * 64 + w * 4 + j;
                float val;
                if (deg == 0) {
                    val = 1.0f;
                } else if (deg == 1) {
                    val = xs;
                } else {
                    // P_{n+1} = ((2n+1) x P_n - n P_{n-1}) / (n+1), n = deg-1
                    const float nf = (float)(deg - 1);
                    val = ((2.0f * nf + 1.0f) * xs * pc - nf * pm) * (1.0f / (nf + 1.0f));
                    pm = pc;
                    pc = val;
                }
                q[j] = val;
            }
            my[lane * 16 + (w ^ (lane & 15))] = q;
        }

        // --- drain: 16 nt instrs, each = 4 runs of 256 B contiguous ---
#pragma unroll
        for (int k = 0; k < 16; ++k) {
            const int s  = k * 4 + (lane >> 4);  // local segment
            const int wd = lane & 15;            // f32x4 word within chunk
            const f32x4 d = my[s * 16 + (wd ^ (s & 15))];
            __builtin_nontemporal_store(
                d, &outv[(size_t)(seg0 + s) * (DEG1 / 4) + c * 16 + wd]);
        }
    }
}

// Diagnostic probe: memset-identical plain-HIP store stream, constant data.
// Grid-stride, 256-thr blocks, 1 KB contiguous per wave-instr, plain stores.
__global__ __launch_bounds__(256) void probe_const_fill(u32x4* __restrict__ ws,
                                                        size_t n4) {
    size_t i = (size_t)blockIdx.x * 256 + threadIdx.x;
    const size_t stride = (size_t)gridDim.x * 256;
    u32x4 v;
    v.x = 0xAAAAAAAAu; v.y = 0xAAAAAAAAu; v.z = 0xAAAAAAAAu; v.w = 0xAAAAAAAAu;
    for (; i < n4; i += stride) {
        ws[i] = v;
    }
}

extern "C" void kernel_launch(void* const* d_in, const int* in_sizes, int n_in,
                              void* d_out, int out_size, void* d_ws, size_t ws_size,
                              hipStream_t stream) {
    const float* x = (const float*)d_in[0];
    float* out = (float*)d_out;
    const int total = in_sizes[0];   // 1,048,576 segments
    const int grid = total / 256;    // 256 segments per block (4 waves x 64)
    LegendreProjection_48644799594943_kernel<<<grid, 256, 0, stream>>>(x, out);

    // Probe: 512 MB constant-pattern write into scratch (timed in-graph).
    const size_t probe_bytes = (size_t)512 * 1024 * 1024;
    if (ws_size >= probe_bytes) {
        const size_t n4 = probe_bytes / 16;   // 33,554,432 uint4
        probe_const_fill<<<2048, 256, 0, stream>>>((u32x4*)d_ws, n4);
    }
}

// Round 13
// 101.391 us; speedup vs baseline: 2.1784x; 2.1784x over previous
//
#include <hip/hip_runtime.h>

// Legendre projection: out[n, dim*128 + deg] = P_deg(2*x[n,dim] - 1)
// 1,048,576 (n,dim) segments x 128 fp32 = 512 MiB output. Write-bound.
//
// FINAL (R11 structure, 101.4 us ≈ 5.35 TB/s effective):
// per-wave barrier-free pipeline; 64 segments/wave; 2 chunks of 64
// degrees; XOR-swizzled LDS staging (conflict-free b128 both sides);
// drain = 16 nontemporal store instrs/chunk, each covering 4 runs of
// 256 B contiguous (full 128B lines).
//
// Roofline evidence (R4-R12): seven structural levers — scatter vs
// contiguous drain, 128B/256B/1KB runs, 4-32 waves/CU, nt vs plain
// (nt +3%), persistent grid, dispatch churn, RFO granule — ALL plateau
// at 101-105 us. R12's decisive probe: a memset-identical plain-HIP
// grid-stride constant fill ran at only ~4.5 TB/s — slower than this
// kernel. The 6.7 TB/s rocclr fillBufferAligned reference (2.1 GB,
// 330 us dispatch) is not reproducible from HIP at this size; ~5.3-5.5
// TB/s is the real HIP streaming-write ceiling. This kernel is AT it.

#define DEG1 128

typedef float f32x4 __attribute__((ext_vector_type(4)));

__global__ __launch_bounds__(256) void LegendreProjection_48644799594943_kernel(
    const float* __restrict__ x, float* __restrict__ out) {
    // Per wave: 64 segs x 16 f32x4 (one 64-degree chunk) = 16 KB.
    // Flat idx = seg*16 + (w ^ (seg&15)); conflict-free b128 both sides.
    __shared__ f32x4 lds[4][1024];

    const int tid  = threadIdx.x;
    const int wave = tid >> 6;
    const int lane = tid & 63;
    const int seg0 = (blockIdx.x * 4 + wave) * 64;  // this wave's 64 segments

    const float xs = 2.0f * x[seg0 + lane] - 1.0f;

    f32x4* my = lds[wave];
    f32x4* outv = reinterpret_cast<f32x4*>(out);

    float pm = 1.0f;  // P_{deg-1}
    float pc = xs;    // P_deg

#pragma unroll
    for (int c = 0; c < 2; ++c) {
        // --- compute 64 degrees for my segment, write swizzled to LDS ---
#pragma unroll
        for (int w = 0; w < 16; ++w) {
            f32x4 q;
#pragma unroll
            for (int j = 0; j < 4; ++j) {
                const int deg = c * 64 + w * 4 + j;
                float val;
                if (deg == 0) {
                    val = 1.0f;
                } else if (deg == 1) {
                    val = xs;
                } else {
                    // P_{n+1} = ((2n+1) x P_n - n P_{n-1}) / (n+1), n = deg-1
                    const float nf = (float)(deg - 1);
                    val = ((2.0f * nf + 1.0f) * xs * pc - nf * pm) * (1.0f / (nf + 1.0f));
                    pm = pc;
                    pc = val;
                }
                q[j] = val;
            }
            my[lane * 16 + (w ^ (lane & 15))] = q;
        }

        // --- drain: 16 nt instrs, each = 4 runs of 256 B contiguous ---
#pragma unroll
        for (int k = 0; k < 16; ++k) {
            const int s  = k * 4 + (lane >> 4);  // local segment
            const int wd = lane & 15;            // f32x4 word within chunk
            const f32x4 d = my[s * 16 + (wd ^ (s & 15))];
            __builtin_nontemporal_store(
                d, &outv[(size_t)(seg0 + s) * (DEG1 / 4) + c * 16 + wd]);
        }
    }
}

extern "C" void kernel_launch(void* const* d_in, const int* in_sizes, int n_in,
                              void* d_out, int out_size, void* d_ws, size_t ws_size,
                              hipStream_t stream) {
    const float* x = (const float*)d_in[0];
    float* out = (float*)d_out;
    const int total = in_sizes[0];   // 1,048,576 segments
    const int grid = total / 256;    // 256 segments per block (4 waves x 64)
    LegendreProjection_48644799594943_kernel<<<grid, 256, 0, stream>>>(x, out);
}